// Round 3
// baseline (877.704 us; speedup 1.0000x reference)
//
#include <hip/hip_runtime.h>
#include <math.h>

// ---------- types ----------
typedef __bf16 bf16x8 __attribute__((ext_vector_type(8)));
typedef float f32x4 __attribute__((ext_vector_type(4)));
typedef unsigned short us4v __attribute__((ext_vector_type(4)));
typedef unsigned short us8v __attribute__((ext_vector_type(8)));

#define NTOK 65536   // B*S = 8*8192 tokens
#define DMODEL 512

// round-to-nearest-even f32 -> bf16 bits
__device__ __forceinline__ unsigned short f2bf(float f) {
  unsigned int u = __float_as_uint(f);
  u += 0x7fffu + ((u >> 16) & 1u);
  return (unsigned short)(u >> 16);
}

// fast tanh-GELU: x * u/(u+1), u = exp(2*0.7978845608*(x + 0.044715 x^3))
__device__ __forceinline__ float gelu_fast(float x) {
  float x3 = x * x * x;
  float u = __expf(1.5957691216057308f * (x + 0.044715f * x3));
  return x * __fdividef(u, u + 1.0f);
}

// async global->LDS, 16B per lane; LDS dest is wave-uniform base (+lane*16 by HW)
__device__ __forceinline__ void async16(const void* g, void* l) {
  __builtin_amdgcn_global_load_lds((const __attribute__((address_space(1))) void*)g,
                                   (__attribute__((address_space(3))) void*)l,
                                   16, 0, 0);
}

// ---------- fp32 -> bf16 weight conversion ----------
__global__ __launch_bounds__(256) void cvt_bf16_kernel(const float4* __restrict__ in,
                                                       us4v* __restrict__ out, int n4) {
  int i = blockIdx.x * 256 + threadIdx.x;
  if (i < n4) {
    float4 v = in[i];
    us4v o;
    o.x = f2bf(v.x); o.y = f2bf(v.y); o.z = f2bf(v.z); o.w = f2bf(v.w);
    out[i] = o;
  }
}

// ---------- LayerNorm: one wave per 512-float row, bf16 output ----------
__global__ __launch_bounds__(256) void ln_kernel(const float* __restrict__ x,
                                                 const float* __restrict__ g,
                                                 const float* __restrict__ b,
                                                 unsigned short* __restrict__ out) {
  const int w = threadIdx.x >> 6;
  const int lane = threadIdx.x & 63;
  const size_t row = (size_t)blockIdx.x * 4 + w;
  const float4* xv = (const float4*)(x + row * DMODEL);
  float4 v0 = xv[lane * 2];
  float4 v1 = xv[lane * 2 + 1];
  float s  = v0.x + v0.y + v0.z + v0.w + v1.x + v1.y + v1.z + v1.w;
  float ss = v0.x*v0.x + v0.y*v0.y + v0.z*v0.z + v0.w*v0.w
           + v1.x*v1.x + v1.y*v1.y + v1.z*v1.z + v1.w*v1.w;
#pragma unroll
  for (int m = 1; m < 64; m <<= 1) {
    s  += __shfl_xor(s, m, 64);
    ss += __shfl_xor(ss, m, 64);
  }
  const float mean = s * (1.0f / DMODEL);
  const float var  = ss * (1.0f / DMODEL) - mean * mean;
  const float rstd = rsqrtf(var + 1e-5f);
  const int c = lane * 8;
  const float4* gv = (const float4*)(g + c);
  const float4* bv = (const float4*)(b + c);
  float4 g0 = gv[0], g1 = gv[1], bb0 = bv[0], bb1 = bv[1];
  us8v o;
  o[0] = f2bf((v0.x - mean) * rstd * g0.x + bb0.x);
  o[1] = f2bf((v0.y - mean) * rstd * g0.y + bb0.y);
  o[2] = f2bf((v0.z - mean) * rstd * g0.z + bb0.z);
  o[3] = f2bf((v0.w - mean) * rstd * g0.w + bb0.w);
  o[4] = f2bf((v1.x - mean) * rstd * g1.x + bb1.x);
  o[5] = f2bf((v1.y - mean) * rstd * g1.y + bb1.y);
  o[6] = f2bf((v1.z - mean) * rstd * g1.z + bb1.z);
  o[7] = f2bf((v1.w - mean) * rstd * g1.w + bb1.w);
  *(us8v*)(out + row * DMODEL + c) = o;
}

// ---------- fragment readers (all indices compile-time after unroll) ----------
template <int HALF>
__device__ __forceinline__ void rd_a(bf16x8* d, const unsigned short* tA,
                                     int wm, int lm, int quad) {
#pragma unroll
  for (int s = 0; s < 2; ++s)
#pragma unroll
    for (int mi = 0; mi < 4; ++mi) {
      const int r = wm * 128 + (HALF * 4 + mi) * 16 + lm;
      d[s * 4 + mi] = *(const bf16x8*)&tA[(r * 8 + ((s * 4 + quad) ^ (r & 7))) * 8];
    }
}

template <int HALF>
__device__ __forceinline__ void rd_b(bf16x8* d, const unsigned short* tB,
                                     int wn, int lm, int quad) {
#pragma unroll
  for (int s = 0; s < 2; ++s)
#pragma unroll
    for (int ni = 0; ni < 2; ++ni) {
      const int c = wn * 64 + (HALF * 2 + ni) * 16 + lm;
      d[s * 2 + ni] = *(const bf16x8*)&tB[(c * 8 + ((s * 4 + quad) ^ (c & 7))) * 8];
    }
}

template <int MO, int NO>
__device__ __forceinline__ void quad_mfma(f32x4 (&acc)[8][4], const bf16x8* a,
                                          const bf16x8* b) {
  __builtin_amdgcn_s_setprio(1);
#pragma unroll
  for (int s = 0; s < 2; ++s)
#pragma unroll
    for (int mi = 0; mi < 4; ++mi)
#pragma unroll
      for (int ni = 0; ni < 2; ++ni)
        acc[MO + mi][NO + ni] = __builtin_amdgcn_mfma_f32_16x16x32_bf16(
            a[s * 4 + mi], b[s * 2 + ni], acc[MO + mi][NO + ni], 0, 0, 0);
  __builtin_amdgcn_s_setprio(0);
}

// ---------- bf16 GEMM, 256x256 tile, wave-pipelined quadrant schedule ----------
// C[M,N] = A[M,K] @ B[N,K]^T (+bias)(+resid)(+gelu)
// 512 threads = 8 waves (2m x 4n), per-wave 128x64 output, acc[8][4] f32x4.
// BK=64, 2 LDS buffers (A 32K + B 32K each) = 128 KiB, 1 block/CU.
//
// Schedule (R3): NO intra-tile barriers. Per wave, ds_reads are issued one
// quadrant AHEAD of their consuming MFMA cluster; the compiler's counted
// lgkmcnt waits let the LDS pipe (~750-1100 cyc/tile/CU) serve under the
// matrix pipe (~2483 cyc/tile/CU) instead of alternating with it (R2's
// lockstep phases serialized these: 23% MfmaUtil).
//   tile top : issue b1,a1 (12 reads) from buf[cur]
//   Q00(a0,b0) -> Q01(a0,b1) -> Q10(a1,b0) -> Q11(a1,b1)   (a0/b0 were issued
//               at the previous tile's bottom; each quad's operands are ~1
//               quadrant of MFMA ahead of their use)
//   barrier    (all waves done reading buf[cur])
//   stage t+2 -> buf[cur] (8x global_load_lds); s_waitcnt vmcnt(8) => tile
//               t+1's 8 loads complete, t+2's stay in flight (T4: never 0)
//   barrier    (buf[cur^1] ready for every wave)
//   bottom     : issue a0,b0 (12 reads) for tile t+1 from buf[cur^1]
// sched_barrier(0) pins read-issue ahead of the MFMA clusters.
// LDS swizzle + staging + vmcnt ledger identical to R2 (harness-verified).
// XCD band scheduling retained (block n -> XCD n%8; bands sized for L2).
template <int EPI, bool EXPERT, typename OutT, int K>
__global__ __launch_bounds__(512, 2) void gemmP(
    const unsigned short* __restrict__ A, const unsigned short* __restrict__ B,
    const float* __restrict__ bias, const float* __restrict__ resid,
    OutT* __restrict__ C, int N) {
  __shared__ alignas(16) unsigned short lds[2][2][16384];  // [buf][A/B][256*64]
  const int tid = threadIdx.x;
  const int w = tid >> 6;
  const int lane = tid & 63;
  const int wm = w >> 2, wn = w & 3;        // 2 x 4 wave grid
  const int quad = lane >> 4, lm = lane & 15;

  // ---- XCD-aware band block swizzle ----
  const int ncol = N >> 8;                  // 2 or 8 column tiles
  const int perx = gridDim.x >> 3;          // grid % 8 == 0
  const int xcd = blockIdx.x & 7;
  const int wk = xcd * perx + (blockIdx.x >> 3);
  const int band_rows = (K == 2048) ? 2 : (ncol >= 8 ? 4 : 8);
  const int bb = band_rows * ncol;
  const int band = wk / bb;
  const int rem = wk - band * bb;
  const int ct = rem / band_rows;
  const int rib = rem - ct * band_rows;
  const size_t row0 = (size_t)(band * band_rows + rib) * 256;
  const int col0 = ct * 256;

  const unsigned short* Bp = B;
  const float* biasp = bias;
  if (EXPERT) {
    const int e = (int)((row0 >> 12) & 7);  // (token/4096) % 8, tiles expert-aligned
    Bp += (size_t)e * (size_t)N * (size_t)K;
    biasp += (size_t)e * (size_t)N;
  }

  // ---- staging addresses (identical to R2, harness-verified) ----
  const int r0 = w * 32 + (lane >> 3);
  const int kg0 = (lane & 7) ^ (lane >> 3);
  const unsigned short* gA = A + (row0 + (size_t)r0) * (size_t)K + kg0 * 8;
  const unsigned short* gB = Bp + ((size_t)col0 + (size_t)r0) * (size_t)K + kg0 * 8;

  auto stageA = [&](int buf, const unsigned short* p) {
    unsigned short* l = &lds[buf][0][(w * 4) * 512];
    async16(p, l);
    async16(p + 8 * K, l + 512);
    async16(p + 16 * K, l + 1024);
    async16(p + 24 * K, l + 1536);
  };
  auto stageB = [&](int buf, const unsigned short* p) {
    unsigned short* l = &lds[buf][1][(w * 4) * 512];
    async16(p, l);
    async16(p + 8 * K, l + 512);
    async16(p + 16 * K, l + 1024);
    async16(p + 24 * K, l + 1536);
  };

  f32x4 acc[8][4] = {};
  bf16x8 a0[8], b0[4], a1[8], b1[4];
  const int NT = K / 64;

  // ---- prologue: stage tiles 0 and 1; pre-issue tile 0's first frag set ----
  stageA(0, gA);
  stageB(0, gB);
  stageA(1, gA + 64);
  stageB(1, gB + 64);
  gA += 128;   // now points at tile-2 source
  gB += 128;
  asm volatile("s_waitcnt vmcnt(8)" ::: "memory");  // tile 0 landed (per wave)
  __builtin_amdgcn_s_barrier();                     // tile 0 landed (all waves)
  rd_a<0>(a0, &lds[0][0][0], wm, lm, quad);
  rd_b<0>(b0, &lds[0][1][0], wn, lm, quad);
  __builtin_amdgcn_sched_barrier(0);

  for (int t = 0; t < NT; ++t) {
    const int cur = t & 1;
    // issue the second frag set for this tile (in flight during Q00/Q01)
    rd_b<1>(b1, &lds[cur][1][0], wn, lm, quad);
    rd_a<1>(a1, &lds[cur][0][0], wm, lm, quad);
    __builtin_amdgcn_sched_barrier(0);
    quad_mfma<0, 0>(acc, a0, b0);
    quad_mfma<0, 2>(acc, a0, b1);
    quad_mfma<4, 0>(acc, a1, b0);
    quad_mfma<4, 2>(acc, a1, b1);
    if (t == NT - 1) break;
    __builtin_amdgcn_s_barrier();            // all waves done reading buf[cur]
    if (t + 2 < NT) {
      stageA(cur, gA);                       // tile t+2 -> buf[cur]
      stageB(cur, gB);
      gA += 64;
      gB += 64;
      asm volatile("s_waitcnt vmcnt(8)" ::: "memory");  // t+1's 8 done
    } else {
      asm volatile("s_waitcnt vmcnt(0)" ::: "memory");  // tail drain
    }
    __builtin_amdgcn_s_barrier();            // buf[cur^1] ready for all waves
    // issue tile t+1's first frag set (in flight across the back-edge)
    rd_a<0>(a0, &lds[cur ^ 1][0][0], wm, lm, quad);
    rd_b<0>(b0, &lds[cur ^ 1][1][0], wn, lm, quad);
    __builtin_amdgcn_sched_barrier(0);
  }

  // ---- epilogue: C/D layout col=lane&15, row=quad*4+r ----
#pragma unroll
  for (int mi = 0; mi < 8; ++mi) {
#pragma unroll
    for (int ni = 0; ni < 4; ++ni) {
      const int col = col0 + wn * 64 + ni * 16 + lm;
      const float bv = biasp[col];
#pragma unroll
      for (int r = 0; r < 4; ++r) {
        const size_t grow = row0 + (size_t)(wm * 128 + mi * 16 + quad * 4 + r);
        float v = acc[mi][ni][r] + bv;
        if constexpr (EPI == 0) v += resid[grow * (size_t)N + col];
        if constexpr (EPI == 1) v = gelu_fast(v);
        if constexpr (sizeof(OutT) == 4) {
          C[grow * (size_t)N + col] = v;
        } else {
          C[grow * (size_t)N + col] = (OutT)f2bf(v);
        }
      }
    }
  }
}

// ---------- launch ----------
extern "C" void kernel_launch(void* const* d_in, const int* in_sizes, int n_in,
                              void* d_out, int out_size, void* d_ws, size_t ws_size,
                              hipStream_t stream) {
  const float* x      = (const float*)d_in[0];
  const float* ln_g   = (const float*)d_in[1];
  const float* ln_b   = (const float*)d_in[2];
  const float* attn_w = (const float*)d_in[3];
  const float* attn_b = (const float*)d_in[4];
  // d_in[5] = gate_w : logits/top-k are dead code for the output -> skipped
  const float* fc1_w  = (const float*)d_in[6];
  const float* fc1_b  = (const float*)d_in[7];
  const float* fc2_w  = (const float*)d_in[8];
  const float* fc2_b  = (const float*)d_in[9];
  const float* next_w = (const float*)d_in[10];
  const float* next_b = (const float*)d_in[11];

  char* ws = (char*)d_ws;
  const size_t MB = 1024ull * 1024ull;
  unsigned short* wN    = (unsigned short*)(ws);             // 64 MiB: normed, later y
  unsigned short* wXat  = (unsigned short*)(ws + 64 * MB);   // 64 MiB: x_attn (bf16)
  unsigned short* wH    = (unsigned short*)(ws + 128 * MB);  // 256 MiB: gelu(h) (bf16)
  unsigned short* attnbf = (unsigned short*)(ws + 384 * MB); // 0.5 MiB
  unsigned short* fc1bf  = (unsigned short*)(ws + 385 * MB); // 16 MiB
  unsigned short* fc2bf  = (unsigned short*)(ws + 401 * MB); // 16 MiB
  unsigned short* nextbf = (unsigned short*)(ws + 417 * MB); // 0.5 MiB

  // weights fp32 -> bf16 (cheap: ~17.3M elements)
  {
    int n4;
    n4 = (512 * 512) / 4;
    cvt_bf16_kernel<<<dim3((n4 + 255) / 256), dim3(256), 0, stream>>>((const float4*)attn_w, (us4v*)attnbf, n4);
    n4 = (8 * 2048 * 512) / 4;
    cvt_bf16_kernel<<<dim3((n4 + 255) / 256), dim3(256), 0, stream>>>((const float4*)fc1_w, (us4v*)fc1bf, n4);
    n4 = (8 * 512 * 2048) / 4;
    cvt_bf16_kernel<<<dim3((n4 + 255) / 256), dim3(256), 0, stream>>>((const float4*)fc2_w, (us4v*)fc2bf, n4);
    n4 = (512 * 512) / 4;
    cvt_bf16_kernel<<<dim3((n4 + 255) / 256), dim3(256), 0, stream>>>((const float4*)next_w, (us4v*)nextbf, n4);
  }

  // LayerNorm -> wN (bf16 normed)
  ln_kernel<<<dim3(NTOK / 4), dim3(256), 0, stream>>>(x, ln_g, ln_b, wN);

  // x_attn = normed @ attn_w^T + attn_b + x   -> wXat (bf16)
  gemmP<0, false, unsigned short, 512><<<dim3((NTOK / 256) * 2), dim3(512), 0, stream>>>(
      wN, attnbf, attn_b, x, wXat, 512);

  // h = gelu(x_attn @ fc1_w[e]^T + fc1_b[e])  -> wH (bf16)
  gemmP<1, true, unsigned short, 512><<<dim3((NTOK / 256) * 8), dim3(512), 0, stream>>>(
      wXat, fc1bf, fc1_b, nullptr, wH, 2048);

  // y = h @ fc2_w[e]^T + fc2_b[e]             -> wN (bf16, reuse)
  gemmP<2, true, unsigned short, 2048><<<dim3((NTOK / 256) * 2), dim3(512), 0, stream>>>(
      wH, fc2bf, fc2_b, nullptr, wN, 512);

  // out = gelu(y @ next_w^T + next_b)         -> d_out (fp32)
  gemmP<1, false, float, 512><<<dim3((NTOK / 256) * 2), dim3(512), 0, stream>>>(
      wN, nextbf, next_b, nullptr, (float*)d_out, 512);
}

// Round 4
// 864.702 us; speedup vs baseline: 1.0150x; 1.0150x over previous
//
#include <hip/hip_runtime.h>
#include <math.h>

// ---------- types ----------
typedef __bf16 bf16x8 __attribute__((ext_vector_type(8)));
typedef float f32x4 __attribute__((ext_vector_type(4)));
typedef unsigned short us4v __attribute__((ext_vector_type(4)));
typedef unsigned short us8v __attribute__((ext_vector_type(8)));

#define NTOK 65536   // B*S = 8*8192 tokens
#define DMODEL 512

// round-to-nearest-even f32 -> bf16 bits
__device__ __forceinline__ unsigned short f2bf(float f) {
  unsigned int u = __float_as_uint(f);
  u += 0x7fffu + ((u >> 16) & 1u);
  return (unsigned short)(u >> 16);
}

// fast tanh-GELU: x * u/(u+1), u = exp(2*0.7978845608*(x + 0.044715 x^3))
__device__ __forceinline__ float gelu_fast(float x) {
  float x3 = x * x * x;
  float u = __expf(1.5957691216057308f * (x + 0.044715f * x3));
  return x * __fdividef(u, u + 1.0f);
}

// async global->LDS, 16B per lane; LDS dest is wave-uniform base (+lane*16 by HW)
__device__ __forceinline__ void async16(const void* g, void* l) {
  __builtin_amdgcn_global_load_lds((const __attribute__((address_space(1))) void*)g,
                                   (__attribute__((address_space(3))) void*)l,
                                   16, 0, 0);
}

// ---------- fp32 -> bf16 weight conversion ----------
__global__ __launch_bounds__(256) void cvt_bf16_kernel(const float4* __restrict__ in,
                                                       us4v* __restrict__ out, int n4) {
  int i = blockIdx.x * 256 + threadIdx.x;
  if (i < n4) {
    float4 v = in[i];
    us4v o;
    o.x = f2bf(v.x); o.y = f2bf(v.y); o.z = f2bf(v.z); o.w = f2bf(v.w);
    out[i] = o;
  }
}

// ---------- LayerNorm: one wave per 512-float row, bf16 output ----------
__global__ __launch_bounds__(256) void ln_kernel(const float* __restrict__ x,
                                                 const float* __restrict__ g,
                                                 const float* __restrict__ b,
                                                 unsigned short* __restrict__ out) {
  const int w = threadIdx.x >> 6;
  const int lane = threadIdx.x & 63;
  const size_t row = (size_t)blockIdx.x * 4 + w;
  const float4* xv = (const float4*)(x + row * DMODEL);
  float4 v0 = xv[lane * 2];
  float4 v1 = xv[lane * 2 + 1];
  float s  = v0.x + v0.y + v0.z + v0.w + v1.x + v1.y + v1.z + v1.w;
  float ss = v0.x*v0.x + v0.y*v0.y + v0.z*v0.z + v0.w*v0.w
           + v1.x*v1.x + v1.y*v1.y + v1.z*v1.z + v1.w*v1.w;
#pragma unroll
  for (int m = 1; m < 64; m <<= 1) {
    s  += __shfl_xor(s, m, 64);
    ss += __shfl_xor(ss, m, 64);
  }
  const float mean = s * (1.0f / DMODEL);
  const float var  = ss * (1.0f / DMODEL) - mean * mean;
  const float rstd = rsqrtf(var + 1e-5f);
  const int c = lane * 8;
  const float4* gv = (const float4*)(g + c);
  const float4* bv = (const float4*)(b + c);
  float4 g0 = gv[0], g1 = gv[1], bb0 = bv[0], bb1 = bv[1];
  us8v o;
  o[0] = f2bf((v0.x - mean) * rstd * g0.x + bb0.x);
  o[1] = f2bf((v0.y - mean) * rstd * g0.y + bb0.y);
  o[2] = f2bf((v0.z - mean) * rstd * g0.z + bb0.z);
  o[3] = f2bf((v0.w - mean) * rstd * g0.w + bb0.w);
  o[4] = f2bf((v1.x - mean) * rstd * g1.x + bb1.x);
  o[5] = f2bf((v1.y - mean) * rstd * g1.y + bb1.y);
  o[6] = f2bf((v1.z - mean) * rstd * g1.z + bb1.z);
  o[7] = f2bf((v1.w - mean) * rstd * g1.w + bb1.w);
  *(us8v*)(out + row * DMODEL + c) = o;
}

// ---------- bf16 GEMM: C[M,N] = A[M,K] @ B[N,K]^T (+bias)(+resid)(+gelu) ----------
// R1-verified 128x128 tile / 4-wave structure, upgraded with the T3-minimum
// 2-phase recipe: LDS double-buffer + stage-early + single vmcnt(0)+s_barrier
// per K-tile (R1 exposed the full global->LDS latency serially every tile via
// two __syncthreads around the stage).
//
// Per-tile schedule (1 barrier, 1 vmcnt):
//   top    : issue 8x global_load_lds for tile t+1 -> buf[cur^1]
//   middle : 16x ds_read_b128 frags from buf[cur]; 32 MFMA (compiler inserts
//            fine-grained lgkmcnt between reads and MFMA)
//   bottom : s_waitcnt vmcnt(0)  -> tile t+1's stage landed
//            s_barrier           -> all waves done reading buf[cur]
// WAR safety with one barrier: a wave reaches the tile-(t-1) barrier only
// after its reads of buf[cur^1] were lgkm-retired (their consuming MFMAs
// precede the barrier), so restaging buf[cur^1] at the top of tile t cannot
// race any in-flight read.
//
// BK=64, XOR-swizzled LDS: 16B unit (r,kg) at unit index r*8 + (kg ^ (r&7))
//   -> conflict-free ds_read_b128 (measured SQ_LDS_BANK_CONFLICT = 0).
// EPI: 0 = +bias+resid, 1 = +bias then gelu, 2 = +bias
// EXPERT: per-128-row-tile weight/bias block selected by (row/4096)&7
// XCD band scheduling (R1-verified): block n -> XCD n%8; each XCD walks one
// row-band across all column tiles so the A-slab + expert weights stay in L2.
template <int EPI, bool EXPERT, typename OutT, int K>
__global__ __launch_bounds__(256, 2) void gemm_bt3(
    const unsigned short* __restrict__ A, const unsigned short* __restrict__ B,
    const float* __restrict__ bias, const float* __restrict__ resid,
    OutT* __restrict__ C, int N) {
  __shared__ alignas(16) unsigned short tA[2][128 * 64];
  __shared__ alignas(16) unsigned short tB[2][128 * 64];
  const int tid = threadIdx.x;
  const int w = tid >> 6;
  const int lane = tid & 63;
  const int wm = w & 1, wn = w >> 1;
  const int quad = lane >> 4, lm = lane & 15;

  // ---- XCD-aware band block swizzle (identical to R1) ----
  const int ncol = N >> 7;                 // 4 or 16 column tiles
  const int perx = gridDim.x >> 3;         // grid % 8 == 0
  const int xcd = blockIdx.x & 7;
  const int wk = xcd * perx + (blockIdx.x >> 3);
  const int band_rows = (ncol == 16) ? 8 : 16;
  const int bb = band_rows * ncol;
  const int band = wk / bb;
  const int rem = wk - band * bb;
  const int ct = rem / band_rows;
  const int rib = rem - ct * band_rows;
  const size_t row0 = (size_t)(band * band_rows + rib) * 128;
  const int col0 = ct * 128;

  const unsigned short* Bp = B;
  const float* biasp = bias;
  if (EXPERT) {
    const int e = (int)((row0 >> 12) & 7);  // (token/4096) % 8
    Bp += (size_t)e * (size_t)N * (size_t)K;
    biasp += (size_t)e * (size_t)N;
  }

  // ---- staging addresses (identical to R1, harness-verified) ----
  // 16 chunks of 1 KiB per tile (4 per wave); chunk c covers units
  // [c*64, c*64+64); lane l writes unit c*64+l = (r, slot u); source k-unit
  // kg = u ^ (r&7)  (XOR swizzle), global reads stay in one 128B row slice.
  const unsigned short* gA[4];
  const unsigned short* gB[4];
  int lo[4];
#pragma unroll
  for (int j = 0; j < 4; ++j) {
    const int c = w * 4 + j;
    const int f = c * 64 + lane;
    const int r = f >> 3;
    const int u = f & 7;
    const int kg = u ^ (r & 7);
    gA[j] = A + (row0 + (size_t)r) * (size_t)K + kg * 8;
    gB[j] = Bp + ((size_t)col0 + (size_t)r) * (size_t)K + kg * 8;
    lo[j] = c * 512;
  }

  f32x4 acc[4][4] = {};
  const int NT = K / 64;

  // ---- prologue: stage tile 0 -> buf0 ----
#pragma unroll
  for (int j = 0; j < 4; ++j) {
    async16(gA[j], &tA[0][lo[j]]);
    async16(gB[j], &tB[0][lo[j]]);
    gA[j] += 64;
    gB[j] += 64;
  }
  asm volatile("s_waitcnt vmcnt(0)" ::: "memory");
  __builtin_amdgcn_s_barrier();

  for (int t = 0; t < NT; ++t) {
    const int cur = t & 1;
    // stage tile t+1 -> buf[cur^1]; latency hides under this tile's reads+MFMA
    if (t + 1 < NT) {
#pragma unroll
      for (int j = 0; j < 4; ++j) {
        async16(gA[j], &tA[cur ^ 1][lo[j]]);
        async16(gB[j], &tB[cur ^ 1][lo[j]]);
        gA[j] += 64;
        gB[j] += 64;
      }
    }
    bf16x8 af[2][4], bfr[2][4];
#pragma unroll
    for (int s = 0; s < 2; ++s) {
#pragma unroll
      for (int mi = 0; mi < 4; ++mi) {
        const int r = wm * 64 + mi * 16 + lm;
        af[s][mi] = *(const bf16x8*)&tA[cur][(r * 8 + ((s * 4 + quad) ^ (r & 7))) * 8];
      }
#pragma unroll
      for (int ni = 0; ni < 4; ++ni) {
        const int cc = wn * 64 + ni * 16 + lm;
        bfr[s][ni] = *(const bf16x8*)&tB[cur][(cc * 8 + ((s * 4 + quad) ^ (cc & 7))) * 8];
      }
    }
    __builtin_amdgcn_s_setprio(1);
#pragma unroll
    for (int s = 0; s < 2; ++s)
#pragma unroll
      for (int mi = 0; mi < 4; ++mi)
#pragma unroll
        for (int ni = 0; ni < 4; ++ni)
          acc[mi][ni] =
              __builtin_amdgcn_mfma_f32_16x16x32_bf16(af[s][mi], bfr[s][ni], acc[mi][ni], 0, 0, 0);
    __builtin_amdgcn_s_setprio(0);
    // tile t+1 staged complete; all waves past their reads of buf[cur]
    asm volatile("s_waitcnt vmcnt(0)" ::: "memory");
    __builtin_amdgcn_s_barrier();
  }

  // ---- epilogue: C/D layout col=lane&15, row=quad*4+r (identical to R1) ----
#pragma unroll
  for (int mi = 0; mi < 4; ++mi) {
#pragma unroll
    for (int ni = 0; ni < 4; ++ni) {
      const int col = col0 + wn * 64 + ni * 16 + lm;
      const float bv = biasp[col];
#pragma unroll
      for (int r = 0; r < 4; ++r) {
        const size_t grow = row0 + (size_t)(wm * 64 + mi * 16 + quad * 4 + r);
        float v = acc[mi][ni][r] + bv;
        if constexpr (EPI == 0) v += resid[grow * (size_t)N + col];
        if constexpr (EPI == 1) v = gelu_fast(v);
        if constexpr (sizeof(OutT) == 4) {
          C[grow * (size_t)N + col] = v;             // fp32 store (d_out is float*)
        } else {
          C[grow * (size_t)N + col] = (OutT)f2bf(v); // bf16 store (intermediates)
        }
      }
    }
  }
}

// ---------- launch ----------
extern "C" void kernel_launch(void* const* d_in, const int* in_sizes, int n_in,
                              void* d_out, int out_size, void* d_ws, size_t ws_size,
                              hipStream_t stream) {
  const float* x      = (const float*)d_in[0];
  const float* ln_g   = (const float*)d_in[1];
  const float* ln_b   = (const float*)d_in[2];
  const float* attn_w = (const float*)d_in[3];
  const float* attn_b = (const float*)d_in[4];
  // d_in[5] = gate_w : logits/top-k are dead code for the output -> skipped
  const float* fc1_w  = (const float*)d_in[6];
  const float* fc1_b  = (const float*)d_in[7];
  const float* fc2_w  = (const float*)d_in[8];
  const float* fc2_b  = (const float*)d_in[9];
  const float* next_w = (const float*)d_in[10];
  const float* next_b = (const float*)d_in[11];

  char* ws = (char*)d_ws;
  const size_t MB = 1024ull * 1024ull;
  unsigned short* wN    = (unsigned short*)(ws);             // 64 MiB: normed, later y
  unsigned short* wXat  = (unsigned short*)(ws + 64 * MB);   // 64 MiB: x_attn (bf16)
  unsigned short* wH    = (unsigned short*)(ws + 128 * MB);  // 256 MiB: gelu(h) (bf16)
  unsigned short* attnbf = (unsigned short*)(ws + 384 * MB); // 0.5 MiB
  unsigned short* fc1bf  = (unsigned short*)(ws + 385 * MB); // 16 MiB
  unsigned short* fc2bf  = (unsigned short*)(ws + 401 * MB); // 16 MiB
  unsigned short* nextbf = (unsigned short*)(ws + 417 * MB); // 0.5 MiB

  // weights fp32 -> bf16 (cheap: ~17.3M elements)
  {
    int n4;
    n4 = (512 * 512) / 4;
    cvt_bf16_kernel<<<dim3((n4 + 255) / 256), dim3(256), 0, stream>>>((const float4*)attn_w, (us4v*)attnbf, n4);
    n4 = (8 * 2048 * 512) / 4;
    cvt_bf16_kernel<<<dim3((n4 + 255) / 256), dim3(256), 0, stream>>>((const float4*)fc1_w, (us4v*)fc1bf, n4);
    n4 = (8 * 512 * 2048) / 4;
    cvt_bf16_kernel<<<dim3((n4 + 255) / 256), dim3(256), 0, stream>>>((const float4*)fc2_w, (us4v*)fc2bf, n4);
    n4 = (512 * 512) / 4;
    cvt_bf16_kernel<<<dim3((n4 + 255) / 256), dim3(256), 0, stream>>>((const float4*)next_w, (us4v*)nextbf, n4);
  }

  // LayerNorm -> wN (bf16 normed)
  ln_kernel<<<dim3(NTOK / 4), dim3(256), 0, stream>>>(x, ln_g, ln_b, wN);

  // x_attn = normed @ attn_w^T + attn_b + x   -> wXat (bf16)
  gemm_bt3<0, false, unsigned short, 512><<<dim3((NTOK / 128) * 4), dim3(256), 0, stream>>>(
      wN, attnbf, attn_b, x, wXat, 512);

  // h = gelu(x_attn @ fc1_w[e]^T + fc1_b[e])  -> wH (bf16)
  gemm_bt3<1, true, unsigned short, 512><<<dim3((NTOK / 128) * 16), dim3(256), 0, stream>>>(
      wXat, fc1bf, fc1_b, nullptr, wH, 2048);

  // y = h @ fc2_w[e]^T + fc2_b[e]             -> wN (bf16, reuse)
  gemm_bt3<2, true, unsigned short, 2048><<<dim3((NTOK / 128) * 4), dim3(256), 0, stream>>>(
      wH, fc2bf, fc2_b, nullptr, wN, 512);

  // out = gelu(y @ next_w^T + next_b)         -> d_out (fp32)
  gemm_bt3<1, false, float, 512><<<dim3((NTOK / 128) * 4), dim3(256), 0, stream>>>(
      wN, nextbf, next_b, nullptr, (float*)d_out, 512);
}

// Round 5
// 854.267 us; speedup vs baseline: 1.0274x; 1.0122x over previous
//
#include <hip/hip_runtime.h>
#include <math.h>

// ---------- types ----------
typedef __bf16 bf16x8 __attribute__((ext_vector_type(8)));
typedef float f32x4 __attribute__((ext_vector_type(4)));
typedef unsigned short us4v __attribute__((ext_vector_type(4)));
typedef unsigned short us8v __attribute__((ext_vector_type(8)));

#define NTOK 65536   // B*S = 8*8192 tokens
#define DMODEL 512

// round-to-nearest-even f32 -> bf16 bits
__device__ __forceinline__ unsigned short f2bf(float f) {
  unsigned int u = __float_as_uint(f);
  u += 0x7fffu + ((u >> 16) & 1u);
  return (unsigned short)(u >> 16);
}

// fast tanh-GELU: x * u/(u+1), u = exp(2*0.7978845608*(x + 0.044715 x^3))
__device__ __forceinline__ float gelu_fast(float x) {
  float x3 = x * x * x;
  float u = __expf(1.5957691216057308f * (x + 0.044715f * x3));
  return x * __fdividef(u, u + 1.0f);
}

// async global->LDS, 16B per lane; LDS dest is wave-uniform base (+lane*16 by HW)
__device__ __forceinline__ void async16(const void* g, void* l) {
  __builtin_amdgcn_global_load_lds((const __attribute__((address_space(1))) void*)g,
                                   (__attribute__((address_space(3))) void*)l,
                                   16, 0, 0);
}

// ---------- fp32 -> bf16 weight conversion ----------
__global__ __launch_bounds__(256) void cvt_bf16_kernel(const float4* __restrict__ in,
                                                       us4v* __restrict__ out, int n4) {
  int i = blockIdx.x * 256 + threadIdx.x;
  if (i < n4) {
    float4 v = in[i];
    us4v o;
    o.x = f2bf(v.x); o.y = f2bf(v.y); o.z = f2bf(v.z); o.w = f2bf(v.w);
    out[i] = o;
  }
}

// ---------- LayerNorm: one wave per 512-float row, bf16 output ----------
__global__ __launch_bounds__(256) void ln_kernel(const float* __restrict__ x,
                                                 const float* __restrict__ g,
                                                 const float* __restrict__ b,
                                                 unsigned short* __restrict__ out) {
  const int w = threadIdx.x >> 6;
  const int lane = threadIdx.x & 63;
  const size_t row = (size_t)blockIdx.x * 4 + w;
  const float4* xv = (const float4*)(x + row * DMODEL);
  float4 v0 = xv[lane * 2];
  float4 v1 = xv[lane * 2 + 1];
  float s  = v0.x + v0.y + v0.z + v0.w + v1.x + v1.y + v1.z + v1.w;
  float ss = v0.x*v0.x + v0.y*v0.y + v0.z*v0.z + v0.w*v0.w
           + v1.x*v1.x + v1.y*v1.y + v1.z*v1.z + v1.w*v1.w;
#pragma unroll
  for (int m = 1; m < 64; m <<= 1) {
    s  += __shfl_xor(s, m, 64);
    ss += __shfl_xor(ss, m, 64);
  }
  const float mean = s * (1.0f / DMODEL);
  const float var  = ss * (1.0f / DMODEL) - mean * mean;
  const float rstd = rsqrtf(var + 1e-5f);
  const int c = lane * 8;
  const float4* gv = (const float4*)(g + c);
  const float4* bv = (const float4*)(b + c);
  float4 g0 = gv[0], g1 = gv[1], bb0 = bv[0], bb1 = bv[1];
  us8v o;
  o[0] = f2bf((v0.x - mean) * rstd * g0.x + bb0.x);
  o[1] = f2bf((v0.y - mean) * rstd * g0.y + bb0.y);
  o[2] = f2bf((v0.z - mean) * rstd * g0.z + bb0.z);
  o[3] = f2bf((v0.w - mean) * rstd * g0.w + bb0.w);
  o[4] = f2bf((v1.x - mean) * rstd * g1.x + bb1.x);
  o[5] = f2bf((v1.y - mean) * rstd * g1.y + bb1.y);
  o[6] = f2bf((v1.z - mean) * rstd * g1.z + bb1.z);
  o[7] = f2bf((v1.w - mean) * rstd * g1.w + bb1.w);
  *(us8v*)(out + row * DMODEL + c) = o;
}

// ---------- bf16 GEMM: C[M,N] = A[M,K] @ B[N,K]^T (+bias)(+resid)(+gelu) ----------
// R1-verified structure (stage; __syncthreads; ds_read frags; MFMA;
// __syncthreads) with BK=32 instead of 64: LDS tile 16 KiB (was 32), raising
// the blocks/CU cap 5->10. Evidence (R1 vs R4, and m114/m132): inter-block
// TLP hides the per-step vmcnt(0) drain better than any intra-block pipeline
// at lower occupancy. Per-step work halves (4 gloads, 8 ds_read_b128,
// 16 MFMA); totals and accumulation order are bit-identical to R1.
//
// BK=32 swizzle (4 x 16B units per row): unit (r,u) holds k-unit
// u ^ ((r>>1)&3); reader idx = r*4 + (quad ^ ((r>>1)&3)).
//   bank check: 16 lanes (lm=0..15) of a quad -> idx mod 8 =
//   4*(lm&1) + (quad ^ ((lm>>1)&3)) = all 8 values, 2 lanes each -> 2-way
//   aliasing = free. Stage and read use the same involution (both sides).
// EPI: 0 = +bias+resid, 1 = +bias then gelu, 2 = +bias
// EXPERT: per-128-row-tile weight/bias block selected by (row/4096)&7
// XCD band scheduling (R1-verified): block n -> XCD n%8; each XCD walks one
// row-band across all column tiles so the A-slab + expert weights stay in L2.
template <int EPI, bool EXPERT, typename OutT, int K>
__global__ __launch_bounds__(256, 4) void gemm_bt4(
    const unsigned short* __restrict__ A, const unsigned short* __restrict__ B,
    const float* __restrict__ bias, const float* __restrict__ resid,
    OutT* __restrict__ C, int N) {
  __shared__ alignas(16) unsigned short tA[128 * 32];
  __shared__ alignas(16) unsigned short tB[128 * 32];
  const int tid = threadIdx.x;
  const int w = tid >> 6;
  const int lane = tid & 63;
  const int wm = w & 1, wn = w >> 1;
  const int quad = lane >> 4, lm = lane & 15;

  // ---- XCD-aware band block swizzle (identical to R1) ----
  const int ncol = N >> 7;                 // 4 or 16 column tiles
  const int perx = gridDim.x >> 3;         // grid % 8 == 0
  const int xcd = blockIdx.x & 7;
  const int wk = xcd * perx + (blockIdx.x >> 3);
  const int band_rows = (ncol == 16) ? 8 : 16;
  const int bb = band_rows * ncol;
  const int band = wk / bb;
  const int rem = wk - band * bb;
  const int ct = rem / band_rows;
  const int rib = rem - ct * band_rows;
  const size_t row0 = (size_t)(band * band_rows + rib) * 128;
  const int col0 = ct * 128;

  const unsigned short* Bp = B;
  const float* biasp = bias;
  if (EXPERT) {
    const int e = (int)((row0 >> 12) & 7);  // (token/4096) % 8
    Bp += (size_t)e * (size_t)N * (size_t)K;
    biasp += (size_t)e * (size_t)N;
  }

  // ---- staging addresses ----
  // Tile = 8 KiB = 8 chunks of 1 KiB (64 16B-units); wave w owns chunks
  // c = w*2 + j. Unit f = c*64 + lane -> r = c*16 + (lane>>2), u = lane&3,
  // source k-unit kg = u ^ ((r>>1)&3) = (lane&3) ^ ((lane>>3)&3)
  // (independent of c since c*16 keeps r>>1 = c*8 + (lane>>3), c*8 = 0 mod 4).
  const unsigned short* gA[2];
  const unsigned short* gB[2];
  int lo[2];
  const int kg0 = (lane & 3) ^ ((lane >> 3) & 3);
#pragma unroll
  for (int j = 0; j < 2; ++j) {
    const int c = w * 2 + j;
    const int r = c * 16 + (lane >> 2);
    gA[j] = A + (row0 + (size_t)r) * (size_t)K + kg0 * 8;
    gB[j] = Bp + ((size_t)col0 + (size_t)r) * (size_t)K + kg0 * 8;
    lo[j] = c * 512;  // ushort offset of chunk c (1 KiB)
  }

  f32x4 acc[4][4] = {};

  for (int k0 = 0; k0 < K; k0 += 32) {
#pragma unroll
    for (int j = 0; j < 2; ++j) {
      async16(gA[j], &tA[lo[j]]);
      async16(gB[j], &tB[lo[j]]);
      gA[j] += 32;
      gB[j] += 32;
    }
    __syncthreads();
    bf16x8 af[4], bfr[4];
#pragma unroll
    for (int mi = 0; mi < 4; ++mi) {
      const int r = wm * 64 + mi * 16 + lm;
      af[mi] = *(const bf16x8*)&tA[(r * 4 + (quad ^ ((r >> 1) & 3))) * 8];
    }
#pragma unroll
    for (int ni = 0; ni < 4; ++ni) {
      const int cc = wn * 64 + ni * 16 + lm;
      bfr[ni] = *(const bf16x8*)&tB[(cc * 4 + (quad ^ ((cc >> 1) & 3))) * 8];
    }
    __builtin_amdgcn_s_setprio(1);
#pragma unroll
    for (int mi = 0; mi < 4; ++mi)
#pragma unroll
      for (int ni = 0; ni < 4; ++ni)
        acc[mi][ni] =
            __builtin_amdgcn_mfma_f32_16x16x32_bf16(af[mi], bfr[ni], acc[mi][ni], 0, 0, 0);
    __builtin_amdgcn_s_setprio(0);
    __syncthreads();
  }

  // ---- epilogue: C/D layout col=lane&15, row=quad*4+r (identical to R1) ----
#pragma unroll
  for (int mi = 0; mi < 4; ++mi) {
#pragma unroll
    for (int ni = 0; ni < 4; ++ni) {
      const int col = col0 + wn * 64 + ni * 16 + lm;
      const float bv = biasp[col];
#pragma unroll
      for (int r = 0; r < 4; ++r) {
        const size_t grow = row0 + (size_t)(wm * 64 + mi * 16 + quad * 4 + r);
        float v = acc[mi][ni][r] + bv;
        if constexpr (EPI == 0) v += resid[grow * (size_t)N + col];
        if constexpr (EPI == 1) v = gelu_fast(v);
        if constexpr (sizeof(OutT) == 4) {
          C[grow * (size_t)N + col] = v;             // fp32 store (d_out is float*)
        } else {
          C[grow * (size_t)N + col] = (OutT)f2bf(v); // bf16 store (intermediates)
        }
      }
    }
  }
}

// ---------- launch ----------
extern "C" void kernel_launch(void* const* d_in, const int* in_sizes, int n_in,
                              void* d_out, int out_size, void* d_ws, size_t ws_size,
                              hipStream_t stream) {
  const float* x      = (const float*)d_in[0];
  const float* ln_g   = (const float*)d_in[1];
  const float* ln_b   = (const float*)d_in[2];
  const float* attn_w = (const float*)d_in[3];
  const float* attn_b = (const float*)d_in[4];
  // d_in[5] = gate_w : logits/top-k are dead code for the output -> skipped
  const float* fc1_w  = (const float*)d_in[6];
  const float* fc1_b  = (const float*)d_in[7];
  const float* fc2_w  = (const float*)d_in[8];
  const float* fc2_b  = (const float*)d_in[9];
  const float* next_w = (const float*)d_in[10];
  const float* next_b = (const float*)d_in[11];

  char* ws = (char*)d_ws;
  const size_t MB = 1024ull * 1024ull;
  unsigned short* wN    = (unsigned short*)(ws);             // 64 MiB: normed, later y
  unsigned short* wXat  = (unsigned short*)(ws + 64 * MB);   // 64 MiB: x_attn (bf16)
  unsigned short* wH    = (unsigned short*)(ws + 128 * MB);  // 256 MiB: gelu(h) (bf16)
  unsigned short* attnbf = (unsigned short*)(ws + 384 * MB); // 0.5 MiB
  unsigned short* fc1bf  = (unsigned short*)(ws + 385 * MB); // 16 MiB
  unsigned short* fc2bf  = (unsigned short*)(ws + 401 * MB); // 16 MiB
  unsigned short* nextbf = (unsigned short*)(ws + 417 * MB); // 0.5 MiB

  // weights fp32 -> bf16 (cheap: ~17.3M elements)
  {
    int n4;
    n4 = (512 * 512) / 4;
    cvt_bf16_kernel<<<dim3((n4 + 255) / 256), dim3(256), 0, stream>>>((const float4*)attn_w, (us4v*)attnbf, n4);
    n4 = (8 * 2048 * 512) / 4;
    cvt_bf16_kernel<<<dim3((n4 + 255) / 256), dim3(256), 0, stream>>>((const float4*)fc1_w, (us4v*)fc1bf, n4);
    n4 = (8 * 512 * 2048) / 4;
    cvt_bf16_kernel<<<dim3((n4 + 255) / 256), dim3(256), 0, stream>>>((const float4*)fc2_w, (us4v*)fc2bf, n4);
    n4 = (512 * 512) / 4;
    cvt_bf16_kernel<<<dim3((n4 + 255) / 256), dim3(256), 0, stream>>>((const float4*)next_w, (us4v*)nextbf, n4);
  }

  // LayerNorm -> wN (bf16 normed)
  ln_kernel<<<dim3(NTOK / 4), dim3(256), 0, stream>>>(x, ln_g, ln_b, wN);

  // x_attn = normed @ attn_w^T + attn_b + x   -> wXat (bf16)
  gemm_bt4<0, false, unsigned short, 512><<<dim3((NTOK / 128) * 4), dim3(256), 0, stream>>>(
      wN, attnbf, attn_b, x, wXat, 512);

  // h = gelu(x_attn @ fc1_w[e]^T + fc1_b[e])  -> wH (bf16)
  gemm_bt4<1, true, unsigned short, 512><<<dim3((NTOK / 128) * 16), dim3(256), 0, stream>>>(
      wXat, fc1bf, fc1_b, nullptr, wH, 2048);

  // y = h @ fc2_w[e]^T + fc2_b[e]             -> wN (bf16, reuse)
  gemm_bt4<2, true, unsigned short, 2048><<<dim3((NTOK / 128) * 4), dim3(256), 0, stream>>>(
      wH, fc2bf, fc2_b, nullptr, wN, 512);

  // out = gelu(y @ next_w^T + next_b)         -> d_out (fp32)
  gemm_bt4<1, false, float, 512><<<dim3((NTOK / 128) * 4), dim3(256), 0, stream>>>(
      wN, nextbf, next_b, nullptr, (float*)d_out, 512);
}